// Round 10
// baseline (91.015 us; speedup 1.0000x reference)
//
#include <hip/hip_runtime.h>
#include <hip/hip_bf16.h>
#include <math.h>

#define BATCH 256
#define DM    768
#define REPR  1024
#define FF    3072

typedef __attribute__((ext_vector_type(8))) short bf16x8;
typedef __attribute__((ext_vector_type(4))) float f32x4;

__device__ __forceinline__ unsigned bf16rne(float f){
  union{float f; unsigned u;} x; x.f = f;
  return (x.u + 0x7FFFu + ((x.u >> 16) & 1u)) >> 16;
}
__device__ __forceinline__ unsigned pk2(float lo, float hi){
  return bf16rne(lo) | (bf16rne(hi) << 16);
}

// ---------------------------------------------------------------------------
// K1 prep_g1 (r8-exact, 1536 blocks): two independent block families.
//  ids [0,384):    G1 split-4: P1[z] = im @ Wv2 K-slices, B read directly
//                  from raw f32 Wv2 (8-step chains; 4 slices in parallel
//                  amortize cold-HBM load latency -- r9 lesson: do NOT unsplit).
//  ids [384,1536): W1/W2 transpose+convert f32[K][N] -> bf16[N][K], 64x64.
// ---------------------------------------------------------------------------
__global__ __launch_bounds__(256)
void prep_g1(const float* __restrict__ Wv2, const float* __restrict__ W1,
             const float* __restrict__ W2, const float* __restrict__ im,
             ushort* __restrict__ W1t, ushort* __restrict__ W2t,
             float* __restrict__ P1)
{
  const int id = blockIdx.x, tid = threadIdx.x;

  if (id < 384) {                        // ---- G1 blocks ----
    const int z = id / 96, t2 = id % 96, bx = t2 % 12, by = t2 / 12;
    const int lane = tid & 63, wid = tid >> 6;
    const int wr = wid >> 1, wc = wid & 1;
    const int arow = by * 32 + wr * 16 + (lane & 15);
    const int colb = bx * 64 + wc * 32;
    const int kq8  = (lane >> 4) * 8;
    const int kb   = z * 256;            // 8 K-steps per slice

    const float* apf  = im + (size_t)arow * REPR + kb + kq8;
    const int c0 = colb + (lane & 15), c1 = c0 + 16;
    const float* wrow = Wv2 + (size_t)(kb + kq8) * DM;

    f32x4 acc0 = (f32x4)(0.0f), acc1 = (f32x4)(0.0f);

    float4 a0c = *(const float4*)apf, a1c = *(const float4*)(apf + 4);
    float b0c[8], b1c[8];
    #pragma unroll
    for (int j = 0; j < 8; ++j) {
      b0c[j] = wrow[(size_t)j * DM + c0];
      b1c[j] = wrow[(size_t)j * DM + c1];
    }

    for (int s = 0; s < 8; ++s) {
      float4 a0n, a1n; float b0n[8], b1n[8];
      const bool more = (s + 1) < 8;
      if (more) {                        // depth-1 prefetch
        const float* a2 = apf + (s + 1) * 32;
        a0n = *(const float4*)a2; a1n = *(const float4*)(a2 + 4);
        const float* w2r = wrow + (size_t)(s + 1) * 32 * DM;
        #pragma unroll
        for (int j = 0; j < 8; ++j) {
          b0n[j] = w2r[(size_t)j * DM + c0];
          b1n[j] = w2r[(size_t)j * DM + c1];
        }
      }
      union U { unsigned u[4]; bf16x8 v; } afr, bfr0, bfr1;
      afr.u[0] = pk2(a0c.x, a0c.y); afr.u[1] = pk2(a0c.z, a0c.w);
      afr.u[2] = pk2(a1c.x, a1c.y); afr.u[3] = pk2(a1c.z, a1c.w);
      #pragma unroll
      for (int j = 0; j < 4; ++j) {
        bfr0.u[j] = pk2(b0c[2*j], b0c[2*j+1]);
        bfr1.u[j] = pk2(b1c[2*j], b1c[2*j+1]);
      }
      acc0 = __builtin_amdgcn_mfma_f32_16x16x32_bf16(afr.v, bfr0.v, acc0, 0, 0, 0);
      acc1 = __builtin_amdgcn_mfma_f32_16x16x32_bf16(afr.v, bfr1.v, acc1, 0, 0, 0);
      if (more) {
        a0c = a0n; a1c = a1n;
        #pragma unroll
        for (int j = 0; j < 8; ++j) { b0c[j] = b0n[j]; b1c[j] = b1n[j]; }
      }
    }

    const int crow = by * 32 + wr * 16 + (lane >> 4) * 4;
    float* dst = P1 + (size_t)z * BATCH * DM;
    #pragma unroll
    for (int nf = 0; nf < 2; ++nf) {
      const int c = colb + nf * 16 + (lane & 15);
      const f32x4 a = nf ? acc1 : acc0;
      #pragma unroll
      for (int r = 0; r < 4; ++r)
        dst[(size_t)(crow + r) * DM + c] = a[r];
    }
    return;
  }

  // ---- transpose blocks (W1, W2) ----
  const int rel0 = id - 384;
  const float* src; ushort* dst; int K, N, rel;
  if (rel0 < 576) { src = W1; dst = W1t; K = DM; N = FF; rel = rel0; }
  else            { src = W2; dst = W2t; K = FF; N = DM; rel = rel0 - 576; }
  const int ntk = K >> 6;
  const int k0 = (rel % ntk) * 64, n0 = (rel / ntk) * 64;

  __shared__ float lds[64][65];          // +1 pad: column reads 2-way (free)
  #pragma unroll
  for (int p = 0; p < 4; ++p) {
    const int r = p * 16 + (tid >> 4), c4 = (tid & 15) * 4;
    float4 v = *(const float4*)(src + (size_t)(k0 + r) * N + n0 + c4);
    lds[r][c4] = v.x; lds[r][c4+1] = v.y; lds[r][c4+2] = v.z; lds[r][c4+3] = v.w;
  }
  __syncthreads();
  #pragma unroll
  for (int p = 0; p < 4; ++p) {
    const int nn = p * 16 + (tid >> 4), k4 = (tid & 15) * 4;
    uint2 o = { pk2(lds[k4][nn], lds[k4+1][nn]),
                pk2(lds[k4+2][nn], lds[k4+3][nn]) };
    *(uint2*)(dst + (size_t)(n0 + nn) * K + k0 + k4) = o;
  }
}

// ---------------------------------------------------------------------------
// K2 gemm_g2: G2 with fixup fused into the A-path. A-fragment built on the
// fly: x[row][k0..7] = ((P1_0+P1_1)+P1_2+P1_3)+bv2 (EXACT fixup_x order ->
// bit-identical to r8), packed to bf16 in-register. B from W1t (r8-exact).
// Grid (48,8), 24 K-steps, depth-1 prefetch. Epilogue: +b1, exact gelu, bf16.
// ---------------------------------------------------------------------------
__global__ __launch_bounds__(256)
void gemm_g2(const float* __restrict__ P1, const float* __restrict__ bv2,
             const ushort* __restrict__ W1t, const float* __restrict__ b1,
             ushort* __restrict__ tbf)
{
  const int gx = gridDim.x, gy = gridDim.y;           // 48, 8
  int id = blockIdx.y * gx + blockIdx.x;
  id = (id & 7) * ((gx * gy) >> 3) + (id >> 3);       // XCD swizzle (384 % 8 == 0)
  const int bx = id / gy, by = id % gy;

  const int lane = threadIdx.x & 63, wid = threadIdx.x >> 6;
  const int wr = wid >> 1, wc = wid & 1;
  const int arow = by * 32 + wr * 16 + (lane & 15);
  const int colb = bx * 64 + wc * 32;
  const int kq = (lane >> 4) * 8;

  const size_t SL = (size_t)BATCH * DM;
  const float*  pp  = P1 + (size_t)arow * DM + kq;
  const float*  bvp = bv2 + kq;
  const ushort* bp0 = W1t + (size_t)(colb + (lane & 15)) * DM + kq;
  const ushort* bp1 = W1t + (size_t)(colb + 16 + (lane & 15)) * DM + kq;

  f32x4 acc0 = (f32x4)(0.0f), acc1 = (f32x4)(0.0f);
  union U { uint4 q; bf16x8 v; };
  U b0_c, b1_c;
  float4 p_c[4][2], bv_c[2];
  #pragma unroll
  for (int z = 0; z < 4; ++z) {
    p_c[z][0] = *(const float4*)(pp + z * SL);
    p_c[z][1] = *(const float4*)(pp + z * SL + 4);
  }
  bv_c[0] = *(const float4*)bvp;
  bv_c[1] = *(const float4*)(bvp + 4);
  b0_c.q = *(const uint4*)bp0;
  b1_c.q = *(const uint4*)bp1;

  for (int t = 0; t < 24; ++t) {
    U b0_n, b1_n; float4 p_n[4][2], bv_n[2];
    const bool more = (t + 1) < 24;
    if (more) {                          // issue next-step loads before MFMA
      const int o = (t + 1) * 32;
      #pragma unroll
      for (int z = 0; z < 4; ++z) {
        p_n[z][0] = *(const float4*)(pp + z * SL + o);
        p_n[z][1] = *(const float4*)(pp + z * SL + o + 4);
      }
      bv_n[0] = *(const float4*)(bvp + o);
      bv_n[1] = *(const float4*)(bvp + o + 4);
      b0_n.q = *(const uint4*)(bp0 + o);
      b1_n.q = *(const uint4*)(bp1 + o);
    }
    // x slice: ((P1_0 + P1_1) + P1_2 + P1_3) + bv2  (fixup_x order)
    U afr;
    #pragma unroll
    for (int h = 0; h < 2; ++h) {
      float4 s = p_c[0][h];
      s.x += p_c[1][h].x; s.y += p_c[1][h].y; s.z += p_c[1][h].z; s.w += p_c[1][h].w;
      s.x += p_c[2][h].x; s.y += p_c[2][h].y; s.z += p_c[2][h].z; s.w += p_c[2][h].w;
      s.x += p_c[3][h].x; s.y += p_c[3][h].y; s.z += p_c[3][h].z; s.w += p_c[3][h].w;
      s.x += bv_c[h].x;   s.y += bv_c[h].y;   s.z += bv_c[h].z;   s.w += bv_c[h].w;
      if (h == 0) { afr.q.x = pk2(s.x, s.y); afr.q.y = pk2(s.z, s.w); }
      else        { afr.q.z = pk2(s.x, s.y); afr.q.w = pk2(s.z, s.w); }
    }
    acc0 = __builtin_amdgcn_mfma_f32_16x16x32_bf16(afr.v, b0_c.v, acc0, 0, 0, 0);
    acc1 = __builtin_amdgcn_mfma_f32_16x16x32_bf16(afr.v, b1_c.v, acc1, 0, 0, 0);
    if (more) {
      #pragma unroll
      for (int z = 0; z < 4; ++z) { p_c[z][0] = p_n[z][0]; p_c[z][1] = p_n[z][1]; }
      bv_c[0] = bv_n[0]; bv_c[1] = bv_n[1];
      b0_c = b0_n; b1_c = b1_n;
    }
  }

  const int crow = by * 32 + wr * 16 + (lane >> 4) * 4;
  #pragma unroll
  for (int nf = 0; nf < 2; ++nf) {
    const int c = colb + nf * 16 + (lane & 15);
    const f32x4 a = nf ? acc1 : acc0;
    #pragma unroll
    for (int r = 0; r < 4; ++r) {
      float v = a[r] + b1[c];
      v = 0.5f * v * (1.0f + erff(v * 0.70710678118654752f));
      tbf[(size_t)(crow + r) * FF + c] = (ushort)bf16rne(v);
    }
  }
}

// ---------------------------------------------------------------------------
// K3 gemm_rr (r8-exact): register-only GEMM, 32x64 tile, 4 waves 2x2, depth-1
// prefetch. Used for G3 split-8: P3[z] = (t @ W2) K-slices, raw f32 partials.
// ---------------------------------------------------------------------------
__global__ __launch_bounds__(256)
void gemm_rr(const ushort* __restrict__ Abf, const ushort* __restrict__ Bt,
             float* __restrict__ outF, int N, int K, int lda, int kcount)
{
  const int gx = gridDim.x, gy = gridDim.y;
  const int nwg = gx * gy;
  int id = blockIdx.y * gx + blockIdx.x;
  if ((nwg & 7) == 0) id = (id & 7) * (nwg >> 3) + (id >> 3);  // XCD swizzle
  const int bx = id / gy, by = id % gy;

  const int lane = threadIdx.x & 63, wid = threadIdx.x >> 6;
  const int wr = wid >> 1, wc = wid & 1;
  const int arow = by * 32 + wr * 16 + (lane & 15);
  const int colb = bx * 64 + wc * 32;
  const int kq = (lane >> 4) * 8;
  const int kb = blockIdx.z * kcount;

  const ushort* ap  = Abf + (size_t)arow * lda + kb + kq;
  const ushort* bp0 = Bt + (size_t)(colb + (lane & 15)) * K + kb + kq;
  const ushort* bp1 = Bt + (size_t)(colb + 16 + (lane & 15)) * K + kb + kq;

  f32x4 acc0 = (f32x4)(0.0f), acc1 = (f32x4)(0.0f);
  const int nsteps = kcount >> 5;

  union U { uint4 q; bf16x8 v; };
  U a_c, b0_c, b1_c;
  a_c.q  = *(const uint4*)ap;
  b0_c.q = *(const uint4*)bp0;
  b1_c.q = *(const uint4*)bp1;

  for (int t = 0; t < nsteps; ++t) {
    U a_n, b0_n, b1_n;
    const bool more = (t + 1) < nsteps;
    if (more) {                          // issue next-step loads before MFMA
      a_n.q  = *(const uint4*)(ap  + (t + 1) * 32);
      b0_n.q = *(const uint4*)(bp0 + (t + 1) * 32);
      b1_n.q = *(const uint4*)(bp1 + (t + 1) * 32);
    }
    acc0 = __builtin_amdgcn_mfma_f32_16x16x32_bf16(a_c.v, b0_c.v, acc0, 0, 0, 0);
    acc1 = __builtin_amdgcn_mfma_f32_16x16x32_bf16(a_c.v, b1_c.v, acc1, 0, 0, 0);
    if (more) { a_c = a_n; b0_c = b0_n; b1_c = b1_n; }
  }

  const int crow = by * 32 + wr * 16 + (lane >> 4) * 4;
  #pragma unroll
  for (int nf = 0; nf < 2; ++nf) {
    const int c = colb + nf * 16 + (lane & 15);
    const f32x4 a = nf ? acc1 : acc0;
    #pragma unroll
    for (int r = 0; r < 4; ++r)
      outF[(size_t)blockIdx.z * BATCH * N + (size_t)(crow + r) * N + c] = a[r];
  }
}

// ---------------------------------------------------------------------------
// K4 ln_final: x = ((P1_0+P1_1)+P1_2+P1_3)+bv2 (fixup order), then
// y = (x + b2) + P3_0 + ... + P3_7 (r8 LN order), LayerNorm -> out.
// ---------------------------------------------------------------------------
__global__ __launch_bounds__(256)
void ln_final(const float* __restrict__ P1, const float* __restrict__ bv2,
              const float* __restrict__ P3, const float* __restrict__ b2,
              const float* __restrict__ g, const float* __restrict__ be,
              float* __restrict__ out)
{
  const int row = blockIdx.x, tid = threadIdx.x;
  const int lane = tid & 63, wave = tid >> 6;

  float v[3];
  #pragma unroll
  for (int i = 0; i < 3; ++i) {
    const int c = tid + i * 256;
    float x = P1[(size_t)row * DM + c];
    #pragma unroll
    for (int z = 1; z < 4; ++z) x += P1[((size_t)z * BATCH + row) * DM + c];
    x += bv2[c];
    float s = x + b2[c];
    #pragma unroll
    for (int z = 0; z < 8; ++z) s += P3[((size_t)z * BATCH + row) * DM + c];
    v[i] = s;
  }

  __shared__ float red[4];
  float s = v[0] + v[1] + v[2];
  #pragma unroll
  for (int o = 32; o > 0; o >>= 1) s += __shfl_down(s, o);
  if (lane == 0) red[wave] = s;
  __syncthreads();
  const float mu = (red[0] + red[1] + red[2] + red[3]) * (1.0f / 768.0f);
  __syncthreads();
  const float d0 = v[0] - mu, d1 = v[1] - mu, d2 = v[2] - mu;
  float q = d0*d0 + d1*d1 + d2*d2;
  #pragma unroll
  for (int o = 32; o > 0; o >>= 1) q += __shfl_down(q, o);
  if (lane == 0) red[wave] = q;
  __syncthreads();
  const float var = (red[0] + red[1] + red[2] + red[3]) * (1.0f / 768.0f);
  const float inv = rsqrtf(var + 1e-12f);

  float* o = out + (size_t)row * DM;
  o[tid      ] = d0 * inv * g[tid      ] + be[tid      ];
  o[tid + 256] = d1 * inv * g[tid + 256] + be[tid + 256];
  o[tid + 512] = d2 * inv * g[tid + 512] + be[tid + 512];
}

// ---------------------------------------------------------------------------
// 4 kernels: [prep(W1,W2) + G1 split-4] -> G2(+fixup fused) -> G3 (split-8)
// -> LN(+fixup fused). All GEMM schedules r8-exact; numerics bit-identical.
// ws ~18.5 MB.
// ---------------------------------------------------------------------------
extern "C" void kernel_launch(void* const* d_in, const int* in_sizes, int n_in,
                              void* d_out, int out_size, void* d_ws, size_t ws_size,
                              hipStream_t stream)
{
  const float* im  = (const float*)d_in[0];
  const float* Wv2 = (const float*)d_in[12];
  const float* bv2 = (const float*)d_in[13];
  const float* W1  = (const float*)d_in[14];
  const float* b1  = (const float*)d_in[15];
  const float* W2  = (const float*)d_in[16];
  const float* b2  = (const float*)d_in[17];
  const float* g   = (const float*)d_in[18];
  const float* be  = (const float*)d_in[19];
  float* out = (float*)d_out;

  char* w = (char*)d_ws;
  ushort* W1t = (ushort*)(w);                // 3072*768*2  = 4718592
  ushort* W2t = (ushort*)(w + 4718592);      // 768*3072*2  = 4718592
  ushort* tbf = (ushort*)(w + 9437184);      // 256*3072*2  = 1572864
  float*  P1  = (float*) (w + 11010048);     // 4*256*768*4 = 3145728
  float*  P3  = (float*) (w + 14155776);     // 8*256*768*4 = 6291456 -> 20.4MB

  // K1: W1/W2 transpose + G1 split-4 (P1[z] = im @ Wv2 slices, direct f32 B)
  prep_g1<<<1536, 256, 0, stream>>>(Wv2, W1, W2, im, W1t, W2t, P1);
  // K2: tbf = bf16(gelu((sum P1 + bv2) @ W1 + b1))   (M=256,N=3072,K=768)
  gemm_g2<<<dim3(48, 8, 1), 256, 0, stream>>>(P1, bv2, W1t, b1, tbf);
  // K3: P3[z] = (t @ W2) K-slices                    (M=256,N=768,K=3072, split-8)
  gemm_rr<<<dim3(12, 8, 8), 256, 0, stream>>>(tbf, W2t, P3, DM, FF, FF, 384);
  // K4: LN(sum P1 + bv2 + sum P3 + b2) -> out
  ln_final<<<BATCH, 256, 0, stream>>>(P1, bv2, P3, b2, g, be, out);
}

// Round 11
// 66.768 us; speedup vs baseline: 1.3632x; 1.3632x over previous
//
#include <hip/hip_runtime.h>
#include <hip/hip_bf16.h>
#include <math.h>

#define BATCH 256
#define DM    768
#define REPR  1024
#define FF    3072

typedef __attribute__((ext_vector_type(8))) short bf16x8;
typedef __attribute__((ext_vector_type(4))) float f32x4;

__device__ __forceinline__ unsigned bf16rne(float f){
  union{float f; unsigned u;} x; x.f = f;
  return (x.u + 0x7FFFu + ((x.u >> 16) & 1u)) >> 16;
}
__device__ __forceinline__ unsigned pk2(float lo, float hi){
  return bf16rne(lo) | (bf16rne(hi) << 16);
}

// 64x64 transpose tile body (r8-exact): W[K][N] f32 -> Wt[N][K] bf16.
__device__ __forceinline__
void tr_tile(const float* __restrict__ src, ushort* __restrict__ dst,
             int K, int N, int rel, int ntk, float (*lds)[65], int tid)
{
  const int k0 = (rel % ntk) * 64, n0 = (rel / ntk) * 64;
  #pragma unroll
  for (int p = 0; p < 4; ++p) {
    const int r = p * 16 + (tid >> 4), c4 = (tid & 15) * 4;
    float4 v = *(const float4*)(src + (size_t)(k0 + r) * N + n0 + c4);
    lds[r][c4] = v.x; lds[r][c4+1] = v.y; lds[r][c4+2] = v.z; lds[r][c4+3] = v.w;
  }
  __syncthreads();
  #pragma unroll
  for (int p = 0; p < 4; ++p) {
    const int nn = p * 16 + (tid >> 4), k4 = (tid & 15) * 4;
    uint2 o = { pk2(lds[k4][nn], lds[k4+1][nn]),
                pk2(lds[k4+2][nn], lds[k4+3][nn]) };
    *(uint2*)(dst + (size_t)(n0 + nn) * K + k0 + k4) = o;
  }
}

// ---------------------------------------------------------------------------
// K1: ids [0,384) = G1 split-4 (r8-exact loop), epilogue atomicAdd -> xacc
//     (z==0 family folds bv2 in exactly once). ids [384,960) = W1 transpose.
// ---------------------------------------------------------------------------
__global__ __launch_bounds__(256)
void prep_g1(const float* __restrict__ Wv2, const float* __restrict__ W1,
             const float* __restrict__ im, const float* __restrict__ bv2,
             ushort* __restrict__ W1t, float* __restrict__ xacc)
{
  __shared__ float lds[64][65];
  const int id = blockIdx.x, tid = threadIdx.x;

  if (id < 384) {                        // ---- G1 blocks ----
    const int z = id / 96, t2 = id % 96, bx = t2 % 12, by = t2 / 12;
    const int lane = tid & 63, wid = tid >> 6;
    const int wr = wid >> 1, wc = wid & 1;
    const int arow = by * 32 + wr * 16 + (lane & 15);
    const int colb = bx * 64 + wc * 32;
    const int kq8  = (lane >> 4) * 8;
    const int kb   = z * 256;            // 8 K-steps per slice

    const float* apf  = im + (size_t)arow * REPR + kb + kq8;
    const int c0 = colb + (lane & 15), c1 = c0 + 16;
    const float* wrow = Wv2 + (size_t)(kb + kq8) * DM;

    f32x4 acc0 = (f32x4)(0.0f), acc1 = (f32x4)(0.0f);
    float4 a0c = *(const float4*)apf, a1c = *(const float4*)(apf + 4);
    float b0c[8], b1c[8];
    #pragma unroll
    for (int j = 0; j < 8; ++j) {
      b0c[j] = wrow[(size_t)j * DM + c0];
      b1c[j] = wrow[(size_t)j * DM + c1];
    }

    for (int s = 0; s < 8; ++s) {
      float4 a0n, a1n; float b0n[8], b1n[8];
      const bool more = (s + 1) < 8;
      if (more) {                        // depth-1 prefetch
        const float* a2 = apf + (s + 1) * 32;
        a0n = *(const float4*)a2; a1n = *(const float4*)(a2 + 4);
        const float* w2r = wrow + (size_t)(s + 1) * 32 * DM;
        #pragma unroll
        for (int j = 0; j < 8; ++j) {
          b0n[j] = w2r[(size_t)j * DM + c0];
          b1n[j] = w2r[(size_t)j * DM + c1];
        }
      }
      union U { unsigned u[4]; bf16x8 v; } afr, bfr0, bfr1;
      afr.u[0] = pk2(a0c.x, a0c.y); afr.u[1] = pk2(a0c.z, a0c.w);
      afr.u[2] = pk2(a1c.x, a1c.y); afr.u[3] = pk2(a1c.z, a1c.w);
      #pragma unroll
      for (int j = 0; j < 4; ++j) {
        bfr0.u[j] = pk2(b0c[2*j], b0c[2*j+1]);
        bfr1.u[j] = pk2(b1c[2*j], b1c[2*j+1]);
      }
      acc0 = __builtin_amdgcn_mfma_f32_16x16x32_bf16(afr.v, bfr0.v, acc0, 0, 0, 0);
      acc1 = __builtin_amdgcn_mfma_f32_16x16x32_bf16(afr.v, bfr1.v, acc1, 0, 0, 0);
      if (more) {
        a0c = a0n; a1c = a1n;
        #pragma unroll
        for (int j = 0; j < 8; ++j) { b0c[j] = b0n[j]; b1c[j] = b1n[j]; }
      }
    }

    const int crow = by * 32 + wr * 16 + (lane >> 4) * 4;
    #pragma unroll
    for (int nf = 0; nf < 2; ++nf) {
      const int c = colb + nf * 16 + (lane & 15);
      const f32x4 a = nf ? acc1 : acc0;
      const float bb = (z == 0) ? bv2[c] : 0.0f;
      #pragma unroll
      for (int r = 0; r < 4; ++r)
        atomicAdd(&xacc[(size_t)(crow + r) * DM + c], a[r] + bb);
    }
    return;
  }
  tr_tile(W1, W1t, DM, FF, id - 384, 12, lds, tid);
}

// ---------------------------------------------------------------------------
// K2: ids [0,384) = G2 (A packed on the fly from xacc f32: 32B/lane/step,
//     r10 lesson: keep per-step load bytes minimal). ids [384,960) = W2
//     transpose (needed first by K3; BW waves give G2 latency cover).
// ---------------------------------------------------------------------------
__global__ __launch_bounds__(256)
void g2_w2(const float* __restrict__ xacc, const ushort* __restrict__ W1t,
           const float* __restrict__ b1, ushort* __restrict__ tbf,
           const float* __restrict__ W2, ushort* __restrict__ W2t)
{
  __shared__ float lds[64][65];
  const int id0 = blockIdx.x, tid = threadIdx.x;

  if (id0 < 384) {                       // ---- G2 blocks ----
    int id = (id0 & 7) * 48 + (id0 >> 3);          // XCD swizzle (384%8==0)
    const int bx = id / 8, by = id % 8;

    const int lane = tid & 63, wid = tid >> 6;
    const int wr = wid >> 1, wc = wid & 1;
    const int arow = by * 32 + wr * 16 + (lane & 15);
    const int colb = bx * 64 + wc * 32;
    const int kq = (lane >> 4) * 8;

    const float*  pp  = xacc + (size_t)arow * DM + kq;
    const ushort* bp0 = W1t + (size_t)(colb + (lane & 15)) * DM + kq;
    const ushort* bp1 = W1t + (size_t)(colb + 16 + (lane & 15)) * DM + kq;

    f32x4 acc0 = (f32x4)(0.0f), acc1 = (f32x4)(0.0f);
    union U { uint4 q; bf16x8 v; };
    U b0_c, b1_c;
    float4 a0c = *(const float4*)pp, a1c = *(const float4*)(pp + 4);
    b0_c.q = *(const uint4*)bp0;
    b1_c.q = *(const uint4*)bp1;

    for (int t = 0; t < 24; ++t) {
      U b0_n, b1_n; float4 a0n, a1n;
      const bool more = (t + 1) < 24;
      if (more) {                        // issue next-step loads before MFMA
        const int o = (t + 1) * 32;
        a0n = *(const float4*)(pp + o); a1n = *(const float4*)(pp + o + 4);
        b0_n.q = *(const uint4*)(bp0 + o);
        b1_n.q = *(const uint4*)(bp1 + o);
      }
      U afr;
      afr.q.x = pk2(a0c.x, a0c.y); afr.q.y = pk2(a0c.z, a0c.w);
      afr.q.z = pk2(a1c.x, a1c.y); afr.q.w = pk2(a1c.z, a1c.w);
      acc0 = __builtin_amdgcn_mfma_f32_16x16x32_bf16(afr.v, b0_c.v, acc0, 0, 0, 0);
      acc1 = __builtin_amdgcn_mfma_f32_16x16x32_bf16(afr.v, b1_c.v, acc1, 0, 0, 0);
      if (more) { a0c = a0n; a1c = a1n; b0_c = b0_n; b1_c = b1_n; }
    }

    const int crow = by * 32 + wr * 16 + (lane >> 4) * 4;
    #pragma unroll
    for (int nf = 0; nf < 2; ++nf) {
      const int c = colb + nf * 16 + (lane & 15);
      const f32x4 a = nf ? acc1 : acc0;
      #pragma unroll
      for (int r = 0; r < 4; ++r) {
        float v = a[r] + b1[c];
        v = 0.5f * v * (1.0f + erff(v * 0.70710678118654752f));
        tbf[(size_t)(crow + r) * FF + c] = (ushort)bf16rne(v);
      }
    }
    return;
  }
  tr_tile(W2, W2t, FF, DM, id0 - 384, 48, lds, tid);
}

// ---------------------------------------------------------------------------
// K3: G3 split-8 (r8-exact loop), epilogue atomicAdd -> yacc. Grid (12,8,8).
// ---------------------------------------------------------------------------
__global__ __launch_bounds__(256)
void gemm_g3(const ushort* __restrict__ tbf, const ushort* __restrict__ W2t,
             float* __restrict__ yacc)
{
  int id = blockIdx.y * 12 + blockIdx.x;
  id = (id & 7) * 12 + (id >> 3);                  // XCD swizzle (96%8==0)
  const int bx = id / 8, by = id % 8;

  const int lane = threadIdx.x & 63, wid = threadIdx.x >> 6;
  const int wr = wid >> 1, wc = wid & 1;
  const int arow = by * 32 + wr * 16 + (lane & 15);
  const int colb = bx * 64 + wc * 32;
  const int kq = (lane >> 4) * 8;
  const int kb = blockIdx.z * 384;

  const ushort* ap  = tbf + (size_t)arow * FF + kb + kq;
  const ushort* bp0 = W2t + (size_t)(colb + (lane & 15)) * FF + kb + kq;
  const ushort* bp1 = W2t + (size_t)(colb + 16 + (lane & 15)) * FF + kb + kq;

  f32x4 acc0 = (f32x4)(0.0f), acc1 = (f32x4)(0.0f);
  union U { uint4 q; bf16x8 v; };
  U a_c, b0_c, b1_c;
  a_c.q  = *(const uint4*)ap;
  b0_c.q = *(const uint4*)bp0;
  b1_c.q = *(const uint4*)bp1;

  for (int t = 0; t < 12; ++t) {
    U a_n, b0_n, b1_n;
    const bool more = (t + 1) < 12;
    if (more) {                          // issue next-step loads before MFMA
      a_n.q  = *(const uint4*)(ap  + (t + 1) * 32);
      b0_n.q = *(const uint4*)(bp0 + (t + 1) * 32);
      b1_n.q = *(const uint4*)(bp1 + (t + 1) * 32);
    }
    acc0 = __builtin_amdgcn_mfma_f32_16x16x32_bf16(a_c.v, b0_c.v, acc0, 0, 0, 0);
    acc1 = __builtin_amdgcn_mfma_f32_16x16x32_bf16(a_c.v, b1_c.v, acc1, 0, 0, 0);
    if (more) { a_c = a_n; b0_c = b0_n; b1_c = b1_n; }
  }

  const int crow = by * 32 + wr * 16 + (lane >> 4) * 4;
  #pragma unroll
  for (int nf = 0; nf < 2; ++nf) {
    const int c = colb + nf * 16 + (lane & 15);
    const f32x4 a = nf ? acc1 : acc0;
    #pragma unroll
    for (int r = 0; r < 4; ++r)
      atomicAdd(&yacc[(size_t)(crow + r) * DM + c], a[r]);
  }
}

// ---------------------------------------------------------------------------
// K4: y = xacc + yacc + b2, LayerNorm -> out. 1 block/row.
// ---------------------------------------------------------------------------
__global__ __launch_bounds__(256)
void ln_final(const float* __restrict__ xacc, const float* __restrict__ yacc,
              const float* __restrict__ b2, const float* __restrict__ g,
              const float* __restrict__ be, float* __restrict__ out)
{
  const int row = blockIdx.x, tid = threadIdx.x;
  const int lane = tid & 63, wave = tid >> 6;

  float v[3];
  #pragma unroll
  for (int i = 0; i < 3; ++i) {
    const int c = tid + i * 256;
    v[i] = xacc[(size_t)row * DM + c] + yacc[(size_t)row * DM + c] + b2[c];
  }

  __shared__ float red[4];
  float s = v[0] + v[1] + v[2];
  #pragma unroll
  for (int o = 32; o > 0; o >>= 1) s += __shfl_down(s, o);
  if (lane == 0) red[wave] = s;
  __syncthreads();
  const float mu = (red[0] + red[1] + red[2] + red[3]) * (1.0f / 768.0f);
  __syncthreads();
  const float d0 = v[0] - mu, d1 = v[1] - mu, d2 = v[2] - mu;
  float q = d0*d0 + d1*d1 + d2*d2;
  #pragma unroll
  for (int o = 32; o > 0; o >>= 1) q += __shfl_down(q, o);
  if (lane == 0) red[wave] = q;
  __syncthreads();
  const float var = (red[0] + red[1] + red[2] + red[3]) * (1.0f / 768.0f);
  const float inv = rsqrtf(var + 1e-12f);

  float* o = out + (size_t)row * DM;
  o[tid      ] = d0 * inv * g[tid      ] + be[tid      ];
  o[tid + 256] = d1 * inv * g[tid + 256] + be[tid + 256];
  o[tid + 512] = d2 * inv * g[tid + 512] + be[tid + 512];
}

// ---------------------------------------------------------------------------
// memset(xacc,yacc) -> K1[G1-atomic + W1t] -> K2[G2 + W2t] -> K3[G3-atomic]
// -> K4[LN]. 4 kernels + 1 memset node. ws ~12.6 MB.
// ---------------------------------------------------------------------------
extern "C" void kernel_launch(void* const* d_in, const int* in_sizes, int n_in,
                              void* d_out, int out_size, void* d_ws, size_t ws_size,
                              hipStream_t stream)
{
  const float* im  = (const float*)d_in[0];
  const float* Wv2 = (const float*)d_in[12];
  const float* bv2 = (const float*)d_in[13];
  const float* W1  = (const float*)d_in[14];
  const float* b1  = (const float*)d_in[15];
  const float* W2  = (const float*)d_in[16];
  const float* b2  = (const float*)d_in[17];
  const float* g   = (const float*)d_in[18];
  const float* be  = (const float*)d_in[19];
  float* out = (float*)d_out;

  char* w = (char*)d_ws;
  ushort* W1t  = (ushort*)(w);               // 3072*768*2 = 4718592
  ushort* W2t  = (ushort*)(w + 4718592);     // 768*3072*2 = 4718592
  ushort* tbf  = (ushort*)(w + 9437184);     // 256*3072*2 = 1572864
  float*  xacc = (float*) (w + 11010048);    // 256*768*4  = 786432
  float*  yacc = (float*) (w + 11796480);    // 256*768*4  = 786432 -> 12.6MB

  hipMemsetAsync(xacc, 0, 2 * 786432, stream);   // zero xacc+yacc (contiguous)
  // K1: G1 split-4 atomic -> xacc (+bv2 via z0) ; W1 transpose
  prep_g1<<<960, 256, 0, stream>>>(Wv2, W1, im, bv2, W1t, xacc);
  // K2: tbf = bf16(gelu(bf16(xacc) @ W1 + b1)) ; W2 transpose
  g2_w2<<<960, 256, 0, stream>>>(xacc, W1t, b1, tbf, W2, W2t);
  // K3: yacc += (t @ W2) K-slices (split-8)
  gemm_g3<<<dim3(12, 8, 8), 256, 0, stream>>>(tbf, W2t, yacc);
  // K4: LN(xacc + yacc + b2) -> out
  ln_final<<<BATCH, 256, 0, stream>>>(xacc, yacc, b2, g, be, out);
}

// Round 12
// 44.882 us; speedup vs baseline: 2.0279x; 1.4876x over previous
//
#include <hip/hip_runtime.h>
#include <hip/hip_bf16.h>
#include <math.h>

#define BATCH 256
#define DM    768
#define REPR  1024
#define FF    3072

typedef __attribute__((ext_vector_type(8))) short bf16x8;
typedef __attribute__((ext_vector_type(4))) float f32x4;

__device__ __forceinline__ unsigned bf16rne(float f){
  union{float f; unsigned u;} x; x.f = f;
  return (x.u + 0x7FFFu + ((x.u >> 16) & 1u)) >> 16;
}
__device__ __forceinline__ unsigned pk2(float lo, float hi){
  return bf16rne(lo) | (bf16rne(hi) << 16);
}

// ---------------------------------------------------------------------------
// K1 gemm_g1: G1 split-4 (r8-exact loop): P1[z] = im @ Wv2 K-slices.
// B read directly from raw f32 Wv2 (16 strided dwords/lane/step; lanes 0-15
// cover 64B contiguous per k-row). Grid (12,8,4).
// ---------------------------------------------------------------------------
__global__ __launch_bounds__(256)
void gemm_g1(const float* __restrict__ Wv2, const float* __restrict__ im,
             float* __restrict__ P1)
{
  const int z = blockIdx.z, bx = blockIdx.x, by = blockIdx.y;
  const int tid = threadIdx.x;
  const int lane = tid & 63, wid = tid >> 6;
  const int wr = wid >> 1, wc = wid & 1;
  const int arow = by * 32 + wr * 16 + (lane & 15);
  const int colb = bx * 64 + wc * 32;
  const int kq8  = (lane >> 4) * 8;
  const int kb   = z * 256;              // 8 K-steps per slice

  const float* apf  = im + (size_t)arow * REPR + kb + kq8;
  const int c0 = colb + (lane & 15), c1 = c0 + 16;
  const float* wrow = Wv2 + (size_t)(kb + kq8) * DM;

  f32x4 acc0 = (f32x4)(0.0f), acc1 = (f32x4)(0.0f);
  float4 a0c = *(const float4*)apf, a1c = *(const float4*)(apf + 4);
  float b0c[8], b1c[8];
  #pragma unroll
  for (int j = 0; j < 8; ++j) {
    b0c[j] = wrow[(size_t)j * DM + c0];
    b1c[j] = wrow[(size_t)j * DM + c1];
  }

  for (int s = 0; s < 8; ++s) {
    float4 a0n, a1n; float b0n[8], b1n[8];
    const bool more = (s + 1) < 8;
    if (more) {                          // depth-1 prefetch
      const float* a2 = apf + (s + 1) * 32;
      a0n = *(const float4*)a2; a1n = *(const float4*)(a2 + 4);
      const float* w2r = wrow + (size_t)(s + 1) * 32 * DM;
      #pragma unroll
      for (int j = 0; j < 8; ++j) {
        b0n[j] = w2r[(size_t)j * DM + c0];
        b1n[j] = w2r[(size_t)j * DM + c1];
      }
    }
    union U { unsigned u[4]; bf16x8 v; } afr, bfr0, bfr1;
    afr.u[0] = pk2(a0c.x, a0c.y); afr.u[1] = pk2(a0c.z, a0c.w);
    afr.u[2] = pk2(a1c.x, a1c.y); afr.u[3] = pk2(a1c.z, a1c.w);
    #pragma unroll
    for (int j = 0; j < 4; ++j) {
      bfr0.u[j] = pk2(b0c[2*j], b0c[2*j+1]);
      bfr1.u[j] = pk2(b1c[2*j], b1c[2*j+1]);
    }
    acc0 = __builtin_amdgcn_mfma_f32_16x16x32_bf16(afr.v, bfr0.v, acc0, 0, 0, 0);
    acc1 = __builtin_amdgcn_mfma_f32_16x16x32_bf16(afr.v, bfr1.v, acc1, 0, 0, 0);
    if (more) {
      a0c = a0n; a1c = a1n;
      #pragma unroll
      for (int j = 0; j < 8; ++j) { b0c[j] = b0n[j]; b1c[j] = b1n[j]; }
    }
  }

  const int crow = by * 32 + wr * 16 + (lane >> 4) * 4;
  float* dst = P1 + (size_t)z * BATCH * DM;
  #pragma unroll
  for (int nf = 0; nf < 2; ++nf) {
    const int c = colb + nf * 16 + (lane & 15);
    const f32x4 a = nf ? acc1 : acc0;
    #pragma unroll
    for (int r = 0; r < 4; ++r)
      dst[(size_t)(crow + r) * DM + c] = a[r];
  }
}

// ---------------------------------------------------------------------------
// K2 fixup_x (r8-exact): x = sum_z P1[z] + bv2 -> xf (f32) + xbf (bf16).
// ---------------------------------------------------------------------------
__global__ __launch_bounds__(256)
void fixup_x(const float* __restrict__ P1, const float* __restrict__ bv2,
             float* __restrict__ xf, ushort* __restrict__ xbf)
{
  const int e = (blockIdx.x * 256 + threadIdx.x) * 4;
  const int c = e % DM;
  float4 s = *(const float4*)(P1 + e);
  #pragma unroll
  for (int z = 1; z < 4; ++z) {
    float4 v = *(const float4*)(P1 + (size_t)z * BATCH * DM + e);
    s.x += v.x; s.y += v.y; s.z += v.z; s.w += v.w;
  }
  float4 bb = *(const float4*)(bv2 + c);
  s.x += bb.x; s.y += bb.y; s.z += bb.z; s.w += bb.w;
  *(float4*)(xf + e) = s;
  uint2 o = { pk2(s.x, s.y), pk2(s.z, s.w) };
  *(uint2*)(xbf + e) = o;
}

// ---------------------------------------------------------------------------
// K3 gemm_g2: A = xbf bf16 (16B/lane/step, r8-exact path); B DIRECT from raw
// f32 W1 [DM][FF] (16 strided dwords/lane/step, pk2 RNE == transpose path ->
// bit-identical). Grid (48,8), 24 steps, depth-1 prefetch. Epi: +b1, gelu.
// ---------------------------------------------------------------------------
__global__ __launch_bounds__(256)
void gemm_g2(const ushort* __restrict__ xbf, const float* __restrict__ W1,
             const float* __restrict__ b1, ushort* __restrict__ tbf)
{
  int id = blockIdx.y * 48 + blockIdx.x;
  id = (id & 7) * 48 + (id >> 3);        // XCD swizzle (384 % 8 == 0)
  const int bx = id / 8, by = id % 8;

  const int lane = threadIdx.x & 63, wid = threadIdx.x >> 6;
  const int wr = wid >> 1, wc = wid & 1;
  const int arow = by * 32 + wr * 16 + (lane & 15);
  const int colb = bx * 64 + wc * 32;
  const int kq = (lane >> 4) * 8;

  const ushort* ap = xbf + (size_t)arow * DM + kq;
  const int c0 = colb + (lane & 15), c1 = c0 + 16;
  const float* wrow = W1 + (size_t)kq * FF;

  f32x4 acc0 = (f32x4)(0.0f), acc1 = (f32x4)(0.0f);
  union U { uint4 q; bf16x8 v; };
  U a_c;
  a_c.q = *(const uint4*)ap;
  float b0c[8], b1c[8];
  #pragma unroll
  for (int j = 0; j < 8; ++j) {
    b0c[j] = wrow[(size_t)j * FF + c0];
    b1c[j] = wrow[(size_t)j * FF + c1];
  }

  for (int t = 0; t < 24; ++t) {
    U a_n; float b0n[8], b1n[8];
    const bool more = (t + 1) < 24;
    if (more) {                          // issue next-step loads before MFMA
      a_n.q = *(const uint4*)(ap + (t + 1) * 32);
      const float* w2r = wrow + (size_t)(t + 1) * 32 * FF;
      #pragma unroll
      for (int j = 0; j < 8; ++j) {
        b0n[j] = w2r[(size_t)j * FF + c0];
        b1n[j] = w2r[(size_t)j * FF + c1];
      }
    }
    union V { unsigned u[4]; bf16x8 v; } bfr0, bfr1;
    #pragma unroll
    for (int j = 0; j < 4; ++j) {
      bfr0.u[j] = pk2(b0c[2*j], b0c[2*j+1]);
      bfr1.u[j] = pk2(b1c[2*j], b1c[2*j+1]);
    }
    acc0 = __builtin_amdgcn_mfma_f32_16x16x32_bf16(a_c.v, bfr0.v, acc0, 0, 0, 0);
    acc1 = __builtin_amdgcn_mfma_f32_16x16x32_bf16(a_c.v, bfr1.v, acc1, 0, 0, 0);
    if (more) {
      a_c = a_n;
      #pragma unroll
      for (int j = 0; j < 8; ++j) { b0c[j] = b0n[j]; b1c[j] = b1n[j]; }
    }
  }

  const int crow = by * 32 + wr * 16 + (lane >> 4) * 4;
  #pragma unroll
  for (int nf = 0; nf < 2; ++nf) {
    const int c = colb + nf * 16 + (lane & 15);
    const f32x4 a = nf ? acc1 : acc0;
    #pragma unroll
    for (int r = 0; r < 4; ++r) {
      float v = a[r] + b1[c];
      v = 0.5f * v * (1.0f + erff(v * 0.70710678118654752f));
      tbf[(size_t)(crow + r) * FF + c] = (ushort)bf16rne(v);
    }
  }
}

// ---------------------------------------------------------------------------
// K4 gemm_g3: A = tbf bf16; B DIRECT from raw f32 W2 [FF][DM]. Split-8,
// grid (12,8,8), 12 steps each. Epi: raw f32 partial -> P3[z].
// ---------------------------------------------------------------------------
__global__ __launch_bounds__(256)
void gemm_g3(const ushort* __restrict__ tbf, const float* __restrict__ W2,
             float* __restrict__ P3)
{
  int id = blockIdx.y * 12 + blockIdx.x;
  id = (id & 7) * 12 + (id >> 3);        // XCD swizzle (96 % 8 == 0)
  const int bx = id / 8, by = id % 8;

  const int lane = threadIdx.x & 63, wid = threadIdx.x >> 6;
  const int wr = wid >> 1, wc = wid & 1;
  const int arow = by * 32 + wr * 16 + (lane & 15);
  const int colb = bx * 64 + wc * 32;
  const int kq = (lane >> 4) * 8;
  const int kb = blockIdx.z * 384;

  const ushort* ap = tbf + (size_t)arow * FF + kb + kq;
  const int c0 = colb + (lane & 15), c1 = c0 + 16;
  const float* wrow = W2 + (size_t)(kb + kq) * DM;

  f32x4 acc0 = (f32x4)(0.0f), acc1 = (f32x4)(0.0f);
  union U { uint4 q; bf16x8 v; };
  U a_c;
  a_c.q = *(const uint4*)ap;
  float b0c[8], b1c[8];
  #pragma unroll
  for (int j = 0; j < 8; ++j) {
    b0c[j] = wrow[(size_t)j * DM + c0];
    b1c[j] = wrow[(size_t)j * DM + c1];
  }

  for (int t = 0; t < 12; ++t) {
    U a_n; float b0n[8], b1n[8];
    const bool more = (t + 1) < 12;
    if (more) {                          // issue next-step loads before MFMA
      a_n.q = *(const uint4*)(ap + (t + 1) * 32);
      const float* w2r = wrow + (size_t)(t + 1) * 32 * DM;
      #pragma unroll
      for (int j = 0; j < 8; ++j) {
        b0n[j] = w2r[(size_t)j * DM + c0];
        b1n[j] = w2r[(size_t)j * DM + c1];
      }
    }
    union V { unsigned u[4]; bf16x8 v; } bfr0, bfr1;
    #pragma unroll
    for (int j = 0; j < 4; ++j) {
      bfr0.u[j] = pk2(b0c[2*j], b0c[2*j+1]);
      bfr1.u[j] = pk2(b1c[2*j], b1c[2*j+1]);
    }
    acc0 = __builtin_amdgcn_mfma_f32_16x16x32_bf16(a_c.v, bfr0.v, acc0, 0, 0, 0);
    acc1 = __builtin_amdgcn_mfma_f32_16x16x32_bf16(a_c.v, bfr1.v, acc1, 0, 0, 0);
    if (more) {
      a_c = a_n;
      #pragma unroll
      for (int j = 0; j < 8; ++j) { b0c[j] = b0n[j]; b1c[j] = b1n[j]; }
    }
  }

  const int crow = by * 32 + wr * 16 + (lane >> 4) * 4;
  float* dst = P3 + (size_t)blockIdx.z * BATCH * DM;
  #pragma unroll
  for (int nf = 0; nf < 2; ++nf) {
    const int c = colb + nf * 16 + (lane & 15);
    const f32x4 a = nf ? acc1 : acc0;
    #pragma unroll
    for (int r = 0; r < 4; ++r)
      dst[(size_t)(crow + r) * DM + c] = a[r];
  }
}

// ---------------------------------------------------------------------------
// K5 ln_final (r8-exact): y = xf + sum_{z<8} P3[z] + b2, LayerNorm -> out.
// ---------------------------------------------------------------------------
__global__ __launch_bounds__(256)
void ln_final(const float* __restrict__ P3, const float* __restrict__ xf,
              const float* __restrict__ b2, const float* __restrict__ g,
              const float* __restrict__ be, float* __restrict__ out)
{
  const int row = blockIdx.x, tid = threadIdx.x;
  const int lane = tid & 63, wave = tid >> 6;

  float v[3];
  #pragma unroll
  for (int i = 0; i < 3; ++i) {
    const int c = tid + i * 256;
    float s = xf[(size_t)row * DM + c] + b2[c];
    #pragma unroll
    for (int z = 0; z < 8; ++z) s += P3[((size_t)z * BATCH + row) * DM + c];
    v[i] = s;
  }

  __shared__ float red[4];
  float s = v[0] + v[1] + v[2];
  #pragma unroll
  for (int o = 32; o > 0; o >>= 1) s += __shfl_down(s, o);
  if (lane == 0) red[wave] = s;
  __syncthreads();
  const float mu = (red[0] + red[1] + red[2] + red[3]) * (1.0f / 768.0f);
  __syncthreads();
  const float d0 = v[0] - mu, d1 = v[1] - mu, d2 = v[2] - mu;
  float q = d0*d0 + d1*d1 + d2*d2;
  #pragma unroll
  for (int o = 32; o > 0; o >>= 1) q += __shfl_down(q, o);
  if (lane == 0) red[wave] = q;
  __syncthreads();
  const float var = (red[0] + red[1] + red[2] + red[3]) * (1.0f / 768.0f);
  const float inv = rsqrtf(var + 1e-12f);

  float* o = out + (size_t)row * DM;
  o[tid      ] = d0 * inv * g[tid      ] + be[tid      ];
  o[tid + 256] = d1 * inv * g[tid + 256] + be[tid + 256];
  o[tid + 512] = d2 * inv * g[tid + 512] + be[tid + 512];
}

// ---------------------------------------------------------------------------
// 5 kernels, NO weight transposes: G1 (direct f32 B, split-4) -> fixup ->
// G2 (direct f32 B) -> G3 (direct f32 B, split-8) -> LN. Bit-identical to r8.
// ws ~11.2 MB.
// ---------------------------------------------------------------------------
extern "C" void kernel_launch(void* const* d_in, const int* in_sizes, int n_in,
                              void* d_out, int out_size, void* d_ws, size_t ws_size,
                              hipStream_t stream)
{
  const float* im  = (const float*)d_in[0];
  const float* Wv2 = (const float*)d_in[12];
  const float* bv2 = (const float*)d_in[13];
  const float* W1  = (const float*)d_in[14];
  const float* b1  = (const float*)d_in[15];
  const float* W2  = (const float*)d_in[16];
  const float* b2  = (const float*)d_in[17];
  const float* g   = (const float*)d_in[18];
  const float* be  = (const float*)d_in[19];
  float* out = (float*)d_out;

  char* w = (char*)d_ws;
  ushort* xbf = (ushort*)(w);                // 256*768*2   = 393216
  ushort* tbf = (ushort*)(w + 393216);       // 256*3072*2  = 1572864
  float*  xf  = (float*) (w + 1966080);      // 256*768*4   = 786432
  float*  P1  = (float*) (w + 2752512);      // 4*256*768*4 = 3145728
  float*  P3  = (float*) (w + 5898240);      // 8*256*768*4 = 6291456 -> 11.2MB

  // K1: P1[z] = im @ Wv2 slices (direct f32 B, split-4)
  gemm_g1<<<dim3(12, 8, 4), 256, 0, stream>>>(Wv2, im, P1);
  // K2: x = sum P1 + bv2 -> xf, xbf
  fixup_x<<<192, 256, 0, stream>>>(P1, bv2, xf, xbf);
  // K3: tbf = bf16(gelu(x @ W1 + b1))   (direct f32 B)
  gemm_g2<<<dim3(48, 8, 1), 256, 0, stream>>>(xbf, W1, b1, tbf);
  // K4: P3[z] = (t @ W2) K-slices       (direct f32 B, split-8)
  gemm_g3<<<dim3(12, 8, 8), 256, 0, stream>>>(tbf, W2, P3);
  // K5: LN(xf + sum P3 + b2) -> out
  ln_final<<<BATCH, 256, 0, stream>>>(P3, xf, b2, g, be, out);
}